// Round 9
// baseline (251.189 us; speedup 1.0000x reference)
//
#include <hip/hip_runtime.h>

// FindInstancePeaks: fused conv backbone + global peak finding.
// crops (128,192,192,1) f32 -> conv1 3x3 s2 SAME (1->32) + relu
//                          -> conv2 3x3 s1 SAME (32->17) = cms (128,96,96,17)
// -> per (b,n): argmax over 96x96, quarter-pixel sign refine, *2, NaN<0.2.
//
// R9: conv2 body identical to R5/R8 (s_load weights -> SGPRs, spill-free).
// Two targeted fixes from R8's counters:
//  (1) 32x16 tiles -> 2304 blocks of 128 thr = exactly 9 jobs/CU (R8's
//      1152 blocks = 4.5/CU -> ~11% imbalance tail).
//  (2) split-parity s_in (even-col / odd-col planes): conv1's stride-2
//      lane pattern (4-way bank conflict, ~1.4e7 cyc since R1) becomes
//      stride-1 conflict-free.

#define NCH 17
#define C1 32
#define TSX 32          // tile width
#define TSY 16          // tile height
#define HTY 18          // h rows needed (tile+2)
#define HTX 34          // h cols needed
#define HS 36           // s_h col stride (floats): 144 B rows, 16B-aligned
#define INR 37          // input patch rows: 2*16+5
#define INC 69          // input patch cols: 2*32+5
#define EW 35           // even-col plane width (cols 0,2,..,68)
#define OW 34           // odd-col plane width  (cols 1,3,..,67)
#define CG 4            // conv1 channels per group
#define NG 8            // groups
#define NTHR 128

__device__ __forceinline__ unsigned long long pack_key(float v, unsigned flat) {
    unsigned ub = __float_as_uint(v);
    ub = (ub & 0x80000000u) ? ~ub : (ub | 0x80000000u);   // monotone float->uint
    return ((unsigned long long)ub << 32) | (unsigned)(~flat); // ~flat: ties -> lowest idx
}

__global__ __launch_bounds__(NTHR, 4) void conv_peaks_kernel(
    const float* __restrict__ crops, const float* __restrict__ W1g,
    const float* __restrict__ b1g, const float* __restrict__ W2g,
    const float* __restrict__ b2g, unsigned long long* __restrict__ peaks) {
    __shared__ float s_in_e[INR * EW];                       // 5180 B
    __shared__ float s_in_o[INR * OW];                       // 5032 B
    __shared__ __align__(16) float s_h[CG * HTY * HS];       // 10368 B

    const int t = threadIdx.x;
    const int b = blockIdx.y;
    const int ty0 = (blockIdx.x / 3) * TSY;     // 6 row-tiles
    const int tx0 = (blockIdx.x % 3) * TSX;     // 3 col-tiles
    const int iy0 = 2 * ty0 - 2;
    const int ix0 = 2 * tx0 - 2;
    const float* cb = crops + b * 192 * 192;

    // --- stage input patch, split by column parity (zero-padded) ---
    for (int p = t; p < INR * INC; p += NTHR) {
        int r = p / INC, cc = p - r * INC;
        int iy = iy0 + r, ix = ix0 + cc;
        float v = 0.f;
        if (iy >= 0 && ix >= 0 && iy < 192 && ix < 192) v = cb[iy * 192 + ix];
        int half = cc >> 1;
        if (cc & 1) s_in_o[r * OW + half] = v;
        else        s_in_e[r * EW + half] = v;
    }

    // thread -> 4 contiguous pixels: row ly (0..15), cols lx0..lx0+3
    const int ly = t >> 3;
    const int lx0 = (t & 7) * 4;
    float acc[NCH][4];
#pragma unroll
    for (int n = 0; n < NCH; ++n)
#pragma unroll
        for (int p = 0; p < 4; ++p) acc[n][p] = 0.f;

#pragma unroll 1
    for (int g = 0; g < NG; ++g) {
        __syncthreads();   // prev conv2 reads / staging done before overwrite

        // conv1 + relu for this group's 4 channels.
        // position (r,cc): input cols 2cc+{0,1,2} -> e[cc], o[cc], e[cc+1]
        // (stride-1 across lanes -> conflict-free)
        for (int p = t; p < HTY * HTX; p += NTHR) {
            int r = p / HTX, cc = p - r * HTX;
            int hy = ty0 - 1 + r, hx = tx0 - 1 + cc;
            bool valid = (hy >= 0) && (hy < 96) && (hx >= 0) && (hx < 96);
            float in9[9];
#pragma unroll
            for (int qy = 0; qy < 3; ++qy) {
                int row = 2 * r + qy;
                in9[qy * 3 + 0] = s_in_e[row * EW + cc];
                in9[qy * 3 + 1] = s_in_o[row * OW + cc];
                in9[qy * 3 + 2] = s_in_e[row * EW + cc + 1];
            }
#pragma unroll
            for (int cl = 0; cl < CG; ++cl) {
                int c = g * CG + cl;
                float a = b1g[c];
#pragma unroll
                for (int q = 0; q < 9; ++q) a = fmaf(in9[q], W1g[q * C1 + c], a);
                a = valid ? fmaxf(a, 0.f) : 0.f;
                s_h[cl * (HTY * HS) + r * HS + cc] = a;
            }
        }
        __syncthreads();

        // conv2 partial: per cl, load 3 h-rows x 6 floats once (LDS), read
        // W2 via uniform s_load (SGPRs - keeps VGPR pressure low), then
        // 612 register-only FMAs.  (R5/R8 proven body.)
#pragma unroll 1
        for (int cl = 0; cl < CG; ++cl) {
            float hrow[3][6];
            const float* hp = s_h + cl * (HTY * HS) + ly * HS + lx0;
#pragma unroll
            for (int r = 0; r < 3; ++r) {
                float4 h4 = *(const float4*)(hp + r * HS);       // ds_read_b128
                float2 h2 = *(const float2*)(hp + r * HS + 4);   // ds_read_b64
                hrow[r][0] = h4.x; hrow[r][1] = h4.y;
                hrow[r][2] = h4.z; hrow[r][3] = h4.w;
                hrow[r][4] = h2.x; hrow[r][5] = h2.y;
            }
            const int c = g * CG + cl;
#pragma unroll
            for (int k = 0; k < 9; ++k) {
                const int ky = k / 3, kx = k - ky * 3;
                const float* wb = W2g + (k * C1 + c) * NCH;  // uniform -> s_load
                float w[NCH];
#pragma unroll
                for (int n = 0; n < NCH; ++n) w[n] = wb[n];
#pragma unroll
                for (int n = 0; n < NCH; ++n)
#pragma unroll
                    for (int p = 0; p < 4; ++p)
                        acc[n][p] = fmaf(hrow[ky][kx + p], w[n], acc[n][p]);
            }
        }
    }

    // --- per-channel argmax: in-thread max over 4 px, then wave reduce ---
    const int yg = ty0 + ly, xg = tx0 + lx0;
    const int lane = t & 63;
#pragma unroll
    for (int n = 0; n < NCH; ++n) {
        float bb = b2g[n];
        unsigned long long pk = pack_key(acc[n][0] + bb, (unsigned)(yg * 96 + xg));
#pragma unroll
        for (int p = 1; p < 4; ++p) {
            unsigned long long o = pack_key(acc[n][p] + bb, (unsigned)(yg * 96 + xg + p));
            if (o > pk) pk = o;
        }
#pragma unroll
        for (int off = 32; off; off >>= 1) {
            unsigned long long o = __shfl_down(pk, off, 64);
            if (o > pk) pk = o;
        }
        if (lane == 0) atomicMax(&peaks[b * NCH + n], pk);
    }
}

// One 64-lane wave per (b,n): decode peak, recompute 4 clipped neighbor cms
// values (b2 cancels in the sign differences), emit (x,y,val).
__global__ __launch_bounds__(64) void refine_kernel(
    const float* __restrict__ crops, const float* __restrict__ W1g,
    const float* __restrict__ b1g, const float* __restrict__ W2g,
    const unsigned long long* __restrict__ peaks, float* __restrict__ out) {
    const int bn = blockIdx.x;          // 0..128*17-1
    const int b = bn / NCH, n = bn % NCH;
    const int lane = threadIdx.x;

    unsigned long long pk = peaks[bn];
    unsigned key = (unsigned)(pk >> 32);
    unsigned fbits = (key & 0x80000000u) ? (key ^ 0x80000000u) : ~key;
    float val = __uint_as_float(fbits);
    int flat = (int)(~(unsigned)(pk & 0xffffffffu));
    int yi = flat / 96, xi = flat - yi * 96;

    // neighbor j: 0:(yi,xi+1) 1:(yi,xi-1) 2:(yi+1,xi) 3:(yi-1,xi), clipped
    const int j = lane >> 4;
    int yy = yi + ((j == 2) ? 1 : 0) - ((j == 3) ? 1 : 0);
    int xx = xi + ((j == 0) ? 1 : 0) - ((j == 1) ? 1 : 0);
    yy = min(max(yy, 0), 95);
    xx = min(max(xx, 0), 95);

    // hoist 7x7 crops patch: rows 2yy-2..2yy+4, cols 2xx-2..2xx+4
    const float* cb = crops + b * 192 * 192;
    float pat[7][7];
#pragma unroll
    for (int r = 0; r < 7; ++r) {
        int iy = 2 * yy - 2 + r;
#pragma unroll
        for (int s = 0; s < 7; ++s) {
            int ix = 2 * xx - 2 + s;
            pat[r][s] = (iy >= 0 && iy < 192 && ix >= 0 && ix < 192)
                            ? cb[iy * 192 + ix] : 0.f;
        }
    }

    float part = 0.f;
#pragma unroll
    for (int ci = 0; ci < 2; ++ci) {
        const int c = (lane & 15) + ci * 16;
        const float bias = b1g[c];
        float w1[9];
#pragma unroll
        for (int q = 0; q < 9; ++q) w1[q] = W1g[q * C1 + c];
#pragma unroll
        for (int dy = 0; dy < 3; ++dy) {
#pragma unroll
            for (int dx = 0; dx < 3; ++dx) {
                int hy = yy - 1 + dy, hx = xx - 1 + dx;
                if (hy >= 0 && hy < 96 && hx >= 0 && hx < 96) {
                    float a = bias;
#pragma unroll
                    for (int qy = 0; qy < 3; ++qy)
#pragma unroll
                        for (int qx = 0; qx < 3; ++qx)
                            a = fmaf(pat[2 * dy + qy][2 * dx + qx],
                                     w1[qy * 3 + qx], a);
                    float hval = fmaxf(a, 0.f);
                    part = fmaf(hval, W2g[((dy * 3 + dx) * C1 + c) * NCH + n], part);
                }
            }
        }
    }
    // sum the 16 lanes of each neighbor group
    for (int off = 8; off; off >>= 1) part += __shfl_down(part, off, 16);
    float g0 = __shfl(part, 0, 64);
    float g1 = __shfl(part, 16, 64);
    float g2 = __shfl(part, 32, 64);
    float g3 = __shfl(part, 48, 64);

    if (lane == 0) {
        float d0 = g0 - g1, d1 = g2 - g3;
        float sx = (d0 > 0.f) ? 1.f : ((d0 < 0.f) ? -1.f : 0.f);
        float sy = (d1 > 0.f) ? 1.f : ((d1 < 0.f) ? -1.f : 0.f);
        float px = ((float)xi + 0.25f * sx) * 2.f;
        float py = ((float)yi + 0.25f * sy) * 2.f;
        if (!(val >= 0.2f)) {
            px = __int_as_float(0x7fc00000);
            py = __int_as_float(0x7fc00000);
        }
        out[bn * 3 + 0] = px;
        out[bn * 3 + 1] = py;
        out[bn * 3 + 2] = val;
    }
}

extern "C" void kernel_launch(void* const* d_in, const int* in_sizes, int n_in,
                              void* d_out, int out_size, void* d_ws, size_t ws_size,
                              hipStream_t stream) {
    const float* crops = (const float*)d_in[0];
    const float* W1 = (const float*)d_in[1];
    const float* b1 = (const float*)d_in[2];
    const float* W2 = (const float*)d_in[3];
    const float* b2 = (const float*)d_in[4];
    float* out = (float*)d_out;
    unsigned long long* peaks = (unsigned long long*)d_ws;

    hipMemsetAsync(d_ws, 0, 128 * NCH * sizeof(unsigned long long), stream);

    dim3 gridB(18, 128);   // 3x6 tiles of 32x16 over 96x96, per image
    conv_peaks_kernel<<<gridB, NTHR, 0, stream>>>(crops, W1, b1, W2, b2, peaks);
    refine_kernel<<<128 * NCH, 64, 0, stream>>>(crops, W1, b1, W2, peaks, out);
}

// Round 10
// 227.331 us; speedup vs baseline: 1.1050x; 1.1050x over previous
//
#include <hip/hip_runtime.h>

// FindInstancePeaks: fused conv backbone + global peak finding.
// crops (128,192,192,1) f32 -> conv1 3x3 s2 SAME (1->32) + relu
//                          -> conv2 3x3 s1 SAME (32->17) = cms (128,96,96,17)
// -> per (b,n): argmax over 96x96, quarter-pixel sign refine, *2, NaN<0.2.
//
// R10: R8 structure byte-for-byte (best: 174us conv), with ONE change:
// the conv2 k-loop's scalar weight loads are software-pipelined
// (w_cur/w_nxt rotation) so k+1's 17 uniform s_loads are issued before
// k's 68 FMAs. W2 (19.6KB) overflows scalar L1, and lockstep blocks
// can't hide the ~150-200cyc scalar-L2 latency; doubling the cover to
// ~270cyc of FMAs takes the lgkm wait off the dependence chain.
// (R9 lessons: 128-thr tiles regress; conflicts are argmax-shuffle
// artifacts, not conv LDS - stop chasing them.)

#define NCH 17
#define C1 32
#define TS2 32          // cms tile (32x32)
#define HT2 34          // h rows/cols needed (tile+2)
#define HS 36           // s_h col stride (floats): 144 B rows, 16B-aligned
#define IN2 69          // input patch: 2*32+5
#define CG 4            // conv1 channels per group
#define NG 8            // groups

__device__ __forceinline__ unsigned long long pack_key(float v, unsigned flat) {
    unsigned ub = __float_as_uint(v);
    ub = (ub & 0x80000000u) ? ~ub : (ub | 0x80000000u);   // monotone float->uint
    return ((unsigned long long)ub << 32) | (unsigned)(~flat); // ~flat: ties -> lowest idx
}

__global__ __launch_bounds__(256, 4) void conv_peaks_kernel(
    const float* __restrict__ crops, const float* __restrict__ W1g,
    const float* __restrict__ b1g, const float* __restrict__ W2g,
    const float* __restrict__ b2g, unsigned long long* __restrict__ peaks) {
    __shared__ float s_in[IN2 * IN2];                        // 19044 B
    __shared__ __align__(16) float s_h[CG * HT2 * HS];       // 19584 B

    const int t = threadIdx.x;
    const int b = blockIdx.y;
    const int ty0 = (blockIdx.x / 3) * TS2;
    const int tx0 = (blockIdx.x % 3) * TS2;
    const int iy0 = 2 * ty0 - 2;
    const int ix0 = 2 * tx0 - 2;
    const float* cb = crops + b * 192 * 192;

    // --- stage input patch (zero-padded at image borders) ---
    for (int p = t; p < IN2 * IN2; p += 256) {
        int r = p / IN2, cc = p - r * IN2;
        int iy = iy0 + r, ix = ix0 + cc;
        float v = 0.f;
        if (iy >= 0 && ix >= 0 && iy < 192 && ix < 192) v = cb[iy * 192 + ix];
        s_in[p] = v;
    }

    // thread -> 4 contiguous pixels: row ly, cols lx0..lx0+3
    const int ly = t >> 3;            // 0..31
    const int lx0 = (t & 7) * 4;      // 0,4,...,28
    float acc[NCH][4];
#pragma unroll
    for (int n = 0; n < NCH; ++n)
#pragma unroll
        for (int p = 0; p < 4; ++p) acc[n][p] = 0.f;

#pragma unroll 1
    for (int g = 0; g < NG; ++g) {
        __syncthreads();   // prev conv2 reads / staging done before overwrite

        // conv1 + relu for this group's 4 channels
        for (int p = t; p < HT2 * HT2; p += 256) {
            int r = p / HT2, cc = p - r * HT2;
            int hy = ty0 - 1 + r, hx = tx0 - 1 + cc;
            bool valid = (hy >= 0) && (hy < 96) && (hx >= 0) && (hx < 96);
            float in9[9];
#pragma unroll
            for (int q = 0; q < 9; ++q)
                in9[q] = s_in[(2 * r + q / 3) * IN2 + (2 * cc + q % 3)];
#pragma unroll
            for (int cl = 0; cl < CG; ++cl) {
                int c = g * CG + cl;
                float a = b1g[c];
#pragma unroll
                for (int q = 0; q < 9; ++q) a = fmaf(in9[q], W1g[q * C1 + c], a);
                a = valid ? fmaxf(a, 0.f) : 0.f;
                s_h[cl * (HT2 * HS) + r * HS + cc] = a;
            }
        }
        __syncthreads();

        // conv2 partial: per cl, load 3 h-rows x 6 floats once (LDS); W2 via
        // uniform s_load -> SGPRs, SOFTWARE-PIPELINED one k ahead; then
        // 612 register-only FMAs per cl.
#pragma unroll 1
        for (int cl = 0; cl < CG; ++cl) {
            float hrow[3][6];
            const float* hp = s_h + cl * (HT2 * HS) + ly * HS + lx0;
#pragma unroll
            for (int r = 0; r < 3; ++r) {
                float4 h4 = *(const float4*)(hp + r * HS);       // ds_read_b128
                float2 h2 = *(const float2*)(hp + r * HS + 4);   // ds_read_b64
                hrow[r][0] = h4.x; hrow[r][1] = h4.y;
                hrow[r][2] = h4.z; hrow[r][3] = h4.w;
                hrow[r][4] = h2.x; hrow[r][5] = h2.y;
            }
            const int c = g * CG + cl;
            const float* wbase = W2g + c * NCH;      // + k*C1*NCH per tap
            float wc[NCH], wn[NCH];
#pragma unroll
            for (int n = 0; n < NCH; ++n) wc[n] = wbase[n];      // k=0
#pragma unroll
            for (int k = 0; k < 9; ++k) {
                const int ky = k / 3, kx = k - ky * 3;
                if (k < 8) {
                    const float* wnb = wbase + (k + 1) * C1 * NCH;
#pragma unroll
                    for (int n = 0; n < NCH; ++n) wn[n] = wnb[n]; // prefetch k+1
                }
#pragma unroll
                for (int n = 0; n < NCH; ++n)
#pragma unroll
                    for (int p = 0; p < 4; ++p)
                        acc[n][p] = fmaf(hrow[ky][kx + p], wc[n], acc[n][p]);
                if (k < 8) {
#pragma unroll
                    for (int n = 0; n < NCH; ++n) wc[n] = wn[n];  // rotate (s_mov)
                }
            }
        }
    }

    // --- per-channel argmax: in-thread max over 4 px, then wave reduce ---
    const int yg = ty0 + ly, xg = tx0 + lx0;
    const int lane = t & 63;
#pragma unroll
    for (int n = 0; n < NCH; ++n) {
        float bb = b2g[n];
        unsigned long long pk = pack_key(acc[n][0] + bb, (unsigned)(yg * 96 + xg));
#pragma unroll
        for (int p = 1; p < 4; ++p) {
            unsigned long long o = pack_key(acc[n][p] + bb, (unsigned)(yg * 96 + xg + p));
            if (o > pk) pk = o;
        }
#pragma unroll
        for (int off = 32; off; off >>= 1) {
            unsigned long long o = __shfl_down(pk, off, 64);
            if (o > pk) pk = o;
        }
        if (lane == 0) atomicMax(&peaks[b * NCH + n], pk);
    }
}

// One 64-lane wave per (b,n): decode peak, recompute 4 clipped neighbor cms
// values (b2 cancels in the sign differences), emit (x,y,val).
__global__ __launch_bounds__(64) void refine_kernel(
    const float* __restrict__ crops, const float* __restrict__ W1g,
    const float* __restrict__ b1g, const float* __restrict__ W2g,
    const unsigned long long* __restrict__ peaks, float* __restrict__ out) {
    const int bn = blockIdx.x;          // 0..128*17-1
    const int b = bn / NCH, n = bn % NCH;
    const int lane = threadIdx.x;

    unsigned long long pk = peaks[bn];
    unsigned key = (unsigned)(pk >> 32);
    unsigned fbits = (key & 0x80000000u) ? (key ^ 0x80000000u) : ~key;
    float val = __uint_as_float(fbits);
    int flat = (int)(~(unsigned)(pk & 0xffffffffu));
    int yi = flat / 96, xi = flat - yi * 96;

    // neighbor j: 0:(yi,xi+1) 1:(yi,xi-1) 2:(yi+1,xi) 3:(yi-1,xi), clipped
    const int j = lane >> 4;
    int yy = yi + ((j == 2) ? 1 : 0) - ((j == 3) ? 1 : 0);
    int xx = xi + ((j == 0) ? 1 : 0) - ((j == 1) ? 1 : 0);
    yy = min(max(yy, 0), 95);
    xx = min(max(xx, 0), 95);

    // hoist 7x7 crops patch: rows 2yy-2..2yy+4, cols 2xx-2..2xx+4
    const float* cb = crops + b * 192 * 192;
    float pat[7][7];
#pragma unroll
    for (int r = 0; r < 7; ++r) {
        int iy = 2 * yy - 2 + r;
#pragma unroll
        for (int s = 0; s < 7; ++s) {
            int ix = 2 * xx - 2 + s;
            pat[r][s] = (iy >= 0 && iy < 192 && ix >= 0 && ix < 192)
                            ? cb[iy * 192 + ix] : 0.f;
        }
    }

    float part = 0.f;
#pragma unroll
    for (int ci = 0; ci < 2; ++ci) {
        const int c = (lane & 15) + ci * 16;
        const float bias = b1g[c];
        float w1[9];
#pragma unroll
        for (int q = 0; q < 9; ++q) w1[q] = W1g[q * C1 + c];
#pragma unroll
        for (int dy = 0; dy < 3; ++dy) {
#pragma unroll
            for (int dx = 0; dx < 3; ++dx) {
                int hy = yy - 1 + dy, hx = xx - 1 + dx;
                if (hy >= 0 && hy < 96 && hx >= 0 && hx < 96) {
                    float a = bias;
#pragma unroll
                    for (int qy = 0; qy < 3; ++qy)
#pragma unroll
                        for (int qx = 0; qx < 3; ++qx)
                            a = fmaf(pat[2 * dy + qy][2 * dx + qx],
                                     w1[qy * 3 + qx], a);
                    float hval = fmaxf(a, 0.f);
                    part = fmaf(hval, W2g[((dy * 3 + dx) * C1 + c) * NCH + n], part);
                }
            }
        }
    }
    // sum the 16 lanes of each neighbor group
    for (int off = 8; off; off >>= 1) part += __shfl_down(part, off, 16);
    float g0 = __shfl(part, 0, 64);
    float g1 = __shfl(part, 16, 64);
    float g2 = __shfl(part, 32, 64);
    float g3 = __shfl(part, 48, 64);

    if (lane == 0) {
        float d0 = g0 - g1, d1 = g2 - g3;
        float sx = (d0 > 0.f) ? 1.f : ((d0 < 0.f) ? -1.f : 0.f);
        float sy = (d1 > 0.f) ? 1.f : ((d1 < 0.f) ? -1.f : 0.f);
        float px = ((float)xi + 0.25f * sx) * 2.f;
        float py = ((float)yi + 0.25f * sy) * 2.f;
        if (!(val >= 0.2f)) {
            px = __int_as_float(0x7fc00000);
            py = __int_as_float(0x7fc00000);
        }
        out[bn * 3 + 0] = px;
        out[bn * 3 + 1] = py;
        out[bn * 3 + 2] = val;
    }
}

extern "C" void kernel_launch(void* const* d_in, const int* in_sizes, int n_in,
                              void* d_out, int out_size, void* d_ws, size_t ws_size,
                              hipStream_t stream) {
    const float* crops = (const float*)d_in[0];
    const float* W1 = (const float*)d_in[1];
    const float* b1 = (const float*)d_in[2];
    const float* W2 = (const float*)d_in[3];
    const float* b2 = (const float*)d_in[4];
    float* out = (float*)d_out;
    unsigned long long* peaks = (unsigned long long*)d_ws;

    hipMemsetAsync(d_ws, 0, 128 * NCH * sizeof(unsigned long long), stream);

    dim3 gridB(9, 128);   // 3x3 tiles of 32x32 over 96x96, per image
    conv_peaks_kernel<<<gridB, 256, 0, stream>>>(crops, W1, b1, W2, b2, peaks);
    refine_kernel<<<128 * NCH, 64, 0, stream>>>(crops, W1, b1, W2, peaks, out);
}